// Round 4
// baseline (4586.735 us; speedup 1.0000x reference)
//
#include <hip/hip_runtime.h>
#include <hip/hip_fp16.h>

typedef _Float16 f16x8 __attribute__((ext_vector_type(8)));
typedef float f32x4 __attribute__((ext_vector_type(4)));
typedef unsigned long long u64;

#define NT 128      // 2 waves per block
#define B_ 256
#define D_ 128
#define T_ 512
#define H_ 512

#define NG 8        // batch groups (blockIdx&7 -> round-robin -> one XCD per group)
#define CB 32       // blocks per group
#define BS 32       // batch per group
#define HS 16       // h-cols per block
#define DS 4        // z-dims per block
#define GHSZ (NG * BS * H_)      // 131072 elems per h buffer

#define SC  2048.0f              // 2^11 prescale (keeps all f16 operands normal)
#define S1  (1.0f/2048.0f)       // 2^-11
#define S2  (1.0f/4194304.0f)    // 2^-22

#define MFMA16(A,B,C) __builtin_amdgcn_mfma_f32_16x16x32_f16((A),(B),(C),0,0,0)
#define ALD(p)   __hip_atomic_load((p),  __ATOMIC_RELAXED, __HIP_MEMORY_SCOPE_AGENT)

// ---------------- setup: M = W_ih @ fc_W, split hi/lo(x2^11), lo tiled ------
__global__ __launch_bounds__(256)
void msd_setup_M(const float* __restrict__ W_ih, const float* __restrict__ fc_W,
                 _Float16* __restrict__ Mhi,   // [3H][H] plain
                 _Float16* __restrict__ Mlo)   // fragment-tiled, x2^11
{
    const int r0 = (blockIdx.x >> 1) * 4;
    const int k  = ((blockIdx.x & 1) << 8) + threadIdx.x;
    for (int rr = 0; rr < 4; ++rr) {
        const int R = r0 + rr;
        const float* wrow = W_ih + (size_t)R * D_;
        float s = 0.0f;
        for (int d = 0; d < D_; ++d) s = fmaf(wrow[d], fc_W[(size_t)d * H_ + k], s);
        _Float16 hi = (_Float16)s;
        _Float16 lo = (_Float16)((s - (float)hi) * SC);
        Mhi[(size_t)R * H_ + k] = hi;
        const int t = R >> 9, jj = R & 511;
        const int c = jj >> 4, l16 = jj & 15;
        const int kt = k >> 5, quad = (k >> 3) & 3, j = k & 7;
        const size_t off = ((size_t)(((c * 3 + t) * 16 + kt) * 16 + l16) * 4 + quad) * 8 + j;
        Mlo[off] = lo;
    }
}

// ---------------- transport flavors -----------------------------------------
// L == true : XCD-LOCAL mode (runtime-verified via HW_REG_XCC_ID). Plain
//   write-through stores land in the local L2 after vmcnt(0); consumers use
//   volatile loads + buffer_inv (L1-only invalidate) for freshness. Sync =
//   per-(block,wave) dataflow flags: no RMW serialization, no __syncthreads,
//   waves fully decoupled. Flags are monotonic; a stale-L1 read is stale-LOW,
//   so a false exit is impossible; buffer_inv on the retry path guarantees
//   progress (this exact poll pattern ran correctly in the round-2 kernel).
// L == false: AGENT mode (round-0 proven path): relaxed agent-scope atomics,
//   coherence point = MALL, central counter barrier. Fallback when a group
//   spans XCDs.
template<bool L> __device__ __forceinline__ u64 hld(const u64* p) {
    if constexpr (L) return *p;
    else return __hip_atomic_load(p, __ATOMIC_RELAXED, __HIP_MEMORY_SCOPE_AGENT);
}
template<bool L> __device__ __forceinline__ void hst(unsigned short* p, unsigned short v) {
    if constexpr (L) *p = v;
    else __hip_atomic_store(p, v, __ATOMIC_RELAXED, __HIP_MEMORY_SCOPE_AGENT);
}

// ---------------- main scan loop (templated on transport) -------------------
template<bool L>
__device__ __forceinline__
void run_loop(float* __restrict__ out,
              unsigned short* __restrict__ h1_g, unsigned short* __restrict__ h2_g,
              const _Float16* __restrict__ Mlo_w,
              unsigned* cg, const unsigned* flgW, volatile unsigned* flgPub,
              const _Float16* Whh_s, const _Float16* WhhL_s,
              const _Float16* Mhi_s, const _Float16* fcW_s,
              const int g, const int B0, const int j0, const int d0,
              const int tid, const int lane, const int l16, const int quad, const int bm0,
              const int fcrow, const int* mtb,
              f32x4& zfrag, f32x4* gi_st,
              const float* bhh_l, const float* c_l, const float fcb_l)
{
    float h_own[4] = {0.f, 0.f, 0.f, 0.f};

    for (int i = 1; i <= T_; ++i) {
        const unsigned tgt = (unsigned)(i - 1);
        if constexpr (L) {
            // dataflow wait: my wave-half's 32 producer flags >= i-1.
            // Stale-low volatile reads can't false-exit; inv-on-retry
            // guarantees progress. Usually satisfied on the first read.
            const volatile unsigned* fp =
                (const volatile unsigned*)(flgW + (lane & 31));
            for (;;) {
                unsigned f = *fp;
                if (__ballot((int)(f >= tgt)) == ~0ull) break;
                asm volatile("buffer_inv" ::: "memory");
            }
            // L1 may hold 2-step-old h lines for the buffer we now read
            // (double buffer): invalidate unconditionally AFTER the wait so
            // the kt-loop loads are served fresh from the local L2.
            asm volatile("buffer_inv" ::: "memory");
        }
        // AGENT mode: the barrier at the end of iteration i-1 provides
        // readiness; agent-scope loads bypass L1/L2 anyway.

        const size_t rb = (size_t)((i - 1) & 1) * GHSZ + (size_t)g * (BS * H_);
        const size_t wb = (size_t)(i & 1) * GHSZ + (size_t)g * (BS * H_);
        const u64* rh1 = (const u64*)(h1_g + rb);
        const u64* rh2 = (const u64*)(h2_g + rb);

        f32x4 acc_gh[3], acc2_gh[3], accM1[3], acc2_gi[3], acc_fc;
        {
            f32x4 z4 = {0.f, 0.f, 0.f, 0.f};
            #pragma unroll
            for (int t = 0; t < 3; ++t) { acc_gh[t] = z4; acc2_gh[t] = z4; accM1[t] = z4; acc2_gi[t] = z4; }
            acc_fc = z4;
        }

        // A-fragment base in u64 units: ((bm0+l16)*H_ + quad*8) f16 = /4 u64
        const size_t a64 = ((size_t)(bm0 + l16) * H_ + quad * 8) >> 2;
        #pragma unroll 2
        for (int kt = 0; kt < 16; ++kt) {
            union { u64 q[2]; f16x8 v; } A1, A2;
            A1.q[0] = hld<L>(rh1 + a64 + kt * 8);
            A1.q[1] = hld<L>(rh1 + a64 + kt * 8 + 1);
            A2.q[0] = hld<L>(rh2 + a64 + kt * 8);
            A2.q[1] = hld<L>(rh2 + a64 + kt * 8 + 1);
            f16x8 Ah = A1.v;   // h x 2^11
            f16x8 Al = A2.v;   // resid x 2^22
            const int chunk = ((kt * 4 + quad) ^ (l16 & 7)) * 8;
            #pragma unroll
            for (int t = 0; t < 3; ++t) {
                const int row = (t * 16 + l16) * 512 + chunk;
                f16x8 Bwh = *(const f16x8*)(Whh_s + row);
                f16x8 Bwl = *(const f16x8*)(WhhL_s + row);
                acc_gh[t]  = MFMA16(Ah, Bwh, acc_gh[t]);    // scale 2^11
                acc2_gh[t] = MFMA16(Al, Bwh, acc2_gh[t]);   // scale 2^22
                acc2_gh[t] = MFMA16(Ah, Bwl, acc2_gh[t]);   // scale 2^22
                f16x8 Bmh = *(const f16x8*)(Mhi_s + row);
                f16x8 Bml = *(const f16x8*)(Mlo_w + mtb[t] + kt * 512);
                accM1[t]   = MFMA16(Ah, Bmh, accM1[t]);
                acc2_gi[t] = MFMA16(Al, Bmh, acc2_gi[t]);
                acc2_gi[t] = MFMA16(Ah, Bml, acc2_gi[t]);
            }
            f16x8 Bf = *(const f16x8*)(fcW_s + ((kt * 4 + quad) ^ (fcrow & 7)) * 8 + fcrow * 512);
            acc_fc = MFMA16(Ah, Bf, acc_fc);
        }

        if (i >= 2) {                // gi_st must be updated before h epilogue
            #pragma unroll
            for (int t = 0; t < 3; ++t)
                #pragma unroll
                for (int e = 0; e < 4; ++e)
                    gi_st[t][e] += accM1[t][e] * S1 + acc2_gi[t][e] * S2 + c_l[t];
        }
        if (i <= T_ - 1) {
            unsigned short* wh1 = h1_g + wb;
            unsigned short* wh2 = h2_g + wb;
            #pragma unroll
            for (int e = 0; e < 4; ++e) {
                float ghr = acc_gh[0][e] * S1 + acc2_gh[0][e] * S2 + bhh_l[0];
                float ghz = acc_gh[1][e] * S1 + acc2_gh[1][e] * S2 + bhh_l[1];
                float ghn = acc_gh[2][e] * S1 + acc2_gh[2][e] * S2 + bhh_l[2];
                float r  = 1.0f / (1.0f + __expf(-(gi_st[0][e] + ghr)));
                float zg = 1.0f / (1.0f + __expf(-(gi_st[1][e] + ghz)));
                float xn = gi_st[2][e] + r * ghn;
                float hn = (1.0f - zg) * tanhf(xn) + zg * h_own[e];
                h_own[e] = hn;
                const size_t o = (size_t)(bm0 + quad * 4 + e) * H_ + j0 + l16;
                float hs = hn * SC;
                _Float16 a1 = (_Float16)hs;
                _Float16 a2 = (_Float16)((hs - (float)a1) * SC);
                union { _Float16 f; unsigned short u; } c1, c2;
                c1.f = a1; c2.f = a2;
                hst<L>(wh1 + o, c1.u);   // LOCAL: write-through to local L2
                hst<L>(wh2 + o, c2.u);   // AGENT: relaxed agent-scope store
            }
            if constexpr (L) {
                // publish: drain the wave's h-stores into L2, then release the
                // per-(block,wave) flag with a plain write-through store.
                // No RMW, no __syncthreads: waves fully decoupled.
                asm volatile("s_waitcnt vmcnt(0)" ::: "memory");
                if (lane == 0) *flgPub = (unsigned)i;
            } else {
                // __syncthreads() drains each wave's vmcnt(0) before s_barrier,
                // so all h-stores are at the MALL before tid0 arrives.
                __syncthreads();
                if (tid == 0) {
                    __hip_atomic_fetch_add(cg, 1u, __ATOMIC_RELAXED, __HIP_MEMORY_SCOPE_AGENT);
                    const unsigned target = (unsigned)(CB * i);
                    while (ALD(cg) < target) __builtin_amdgcn_s_sleep(1);
                }
                __syncthreads();
            }
        }
        if (i >= 2 && l16 < DS) {    // out-writes off the inter-block critical path
            const int tcol = i - 1;
            #pragma unroll
            for (int e = 0; e < 4; ++e) {
                zfrag[e] += acc_fc[e] * S1 + fcb_l;
                out[(size_t)(B0 + bm0 + quad * 4 + e) * (D_ * T_) + (size_t)(d0 + l16) * T_ + tcol] = zfrag[e];
            }
        }
    }
}

// ---------------- kernel ----------------------------------------------------
__global__ __launch_bounds__(NT)
void msd_gru_kernel(const float* __restrict__ zin,
                    const float* __restrict__ W_ih,
                    const float* __restrict__ W_hh,
                    const float* __restrict__ b_ih,
                    const float* __restrict__ b_hh,
                    const float* __restrict__ fc_W,
                    const float* __restrict__ fc_b,
                    float* __restrict__ out,
                    unsigned short* __restrict__ h1_g,   // 2 x [NG][BS][H_] (h x 2^11, f16 bits)
                    unsigned short* __restrict__ h2_g,   // 2 x [NG][BS][H_] (resid x 2^22)
                    const _Float16* __restrict__ Mhi_w,  // [3H][H]
                    const _Float16* __restrict__ Mlo_w,  // tiled
                    unsigned* __restrict__ cnt)
{
    const int g   = blockIdx.x & 7;
    const int c   = blockIdx.x >> 3;
    const int B0  = g * BS;
    const int j0  = c * HS;
    const int d0  = c * DS;

    const int tid  = threadIdx.x;
    const int wave = tid >> 6;
    const int lane = tid & 63;
    const int l16  = lane & 15;
    const int quad = lane >> 4;
    const int bm0  = wave * 16;

    // LDS: (48*3 + 5) * 512 * 2 B = 152,576 B.  B-fragments XOR-swizzled:
    // chunk cc (8 f16) of row r stored at cc^(r&7)  -> conflict-free b128 reads.
    __shared__ __attribute__((aligned(16))) _Float16 Whh_s [48 * 512];
    __shared__ __attribute__((aligned(16))) _Float16 WhhL_s[48 * 512];  // x2^11
    __shared__ __attribute__((aligned(16))) _Float16 Mhi_s [48 * 512];
    __shared__ __attribute__((aligned(16))) _Float16 fcW_s [5 * 512];   // row 4 = zeros
    __shared__ int mode_s;

    // ===== phase -1: XCD placement detect (one-time) =========================
    // Group g runs L2-LOCAL iff all 32 of its blocks report the same XCC_ID.
    unsigned* xmask = cnt + 640;   // ws byte 2560, zeroed
    unsigned* ready = cnt + 768;   // ws byte 3072, zeroed
    if (tid == 0) {
        unsigned xcc;
        asm volatile("s_getreg_b32 %0, hwreg(HW_REG_XCC_ID)" : "=s"(xcc));
        __hip_atomic_fetch_or(xmask + g, 1u << (xcc & 31u), __ATOMIC_RELAXED, __HIP_MEMORY_SCOPE_AGENT);
        __hip_atomic_fetch_add(ready, 1u, __ATOMIC_RELAXED, __HIP_MEMORY_SCOPE_AGENT);
        while (ALD(ready) < (unsigned)(NG * CB)) __builtin_amdgcn_s_sleep(4);
        unsigned m = ALD(xmask + g);
        mode_s = (m & (m - 1u)) ? 1 : 0;   // >1 XCD bit set -> AGENT fallback
    }

    // ===== phase 0: z0 into scratch (reuse Mhi_s region), bootstrap state ====
    float* z0s = (float*)Mhi_s;   // 16 KB < 48 KB
    for (int idx = tid; idx < BS * D_; idx += NT) {
        int b = idx >> 7, d = idx & (D_ - 1);
        z0s[idx] = zin[(size_t)(B0 + b) * (D_ * T_) + (size_t)d * T_];
    }
    __syncthreads();

    f32x4 zfrag;
    #pragma unroll
    for (int e = 0; e < 4; ++e)
        zfrag[e] = (l16 < DS) ? z0s[(bm0 + quad * 4 + e) * D_ + d0 + l16] : 0.0f;
    if (l16 < DS) {
        #pragma unroll
        for (int e = 0; e < 4; ++e)
            out[(size_t)(B0 + bm0 + quad * 4 + e) * (D_ * T_) + (size_t)(d0 + l16) * T_] = zfrag[e];
    }
    // gi_1 = W_ih @ z0 + b_ih (exact fp32); c = W_ih @ fc_b; b_hh per lane
    f32x4 gi_st[3];
    float bhh_l[3], c_l[3];
    for (int t = 0; t < 3; ++t) {
        const int gr = t * H_ + j0 + l16;
        const float* wrow = W_ih + (size_t)gr * D_;
        bhh_l[t] = b_hh[gr];
        float s[4] = {b_ih[gr], b_ih[gr], b_ih[gr], b_ih[gr]};
        float cc = 0.0f;
        for (int d = 0; d < D_; ++d) {
            float wv = wrow[d];
            cc = fmaf(wv, fc_b[d], cc);
            #pragma unroll
            for (int e = 0; e < 4; ++e)
                s[e] = fmaf(wv, z0s[(bm0 + quad * 4 + e) * D_ + d], s[e]);
        }
        c_l[t] = cc;
        #pragma unroll
        for (int e = 0; e < 4; ++e) gi_st[t][e] = s[e];
    }
    const float fcb_l = (l16 < DS) ? fc_b[d0 + l16] : 0.0f;
    __syncthreads();   // z0s dead -> Mhi_s region reusable

    // ===== phase 1: stage weights (hi fp16 + lo fp16 x2^11), swizzled ========
    for (int idx = tid; idx < 48 * H_; idx += NT) {
        int r = idx >> 9, k = idx & (H_ - 1);
        int gr = (r >> 4) * H_ + j0 + (r & 15);
        int ccn = k >> 3, j = k & 7;
        int pos = r * 512 + (((ccn ^ (r & 7)) << 3) | j);
        float w = W_hh[(size_t)gr * H_ + k];
        _Float16 hi = (_Float16)w;
        Whh_s [pos] = hi;
        WhhL_s[pos] = (_Float16)((w - (float)hi) * SC);
        Mhi_s [pos] = Mhi_w[(size_t)gr * H_ + k];
    }
    for (int idx = tid; idx < 5 * H_; idx += NT) {
        int r = idx >> 9, k = idx & (H_ - 1);
        int ccn = k >> 3, j = k & 7;
        int pos = r * 512 + (((ccn ^ (r & 7)) << 3) | j);
        float v = (r < DS) ? fc_W[(size_t)(d0 + r) * H_ + k] : 0.0f;
        fcW_s[pos] = (_Float16)v;
    }
    __syncthreads();    // also publishes mode_s

    const int gmode = mode_s;
    unsigned* cg = cnt + g * 64;                           // AGENT central counter
    const unsigned* flgW = cnt + (((g << 1) | wave) << 5); // LOCAL: wave-half's 32 flags
    volatile unsigned* flgPub = (volatile unsigned*)(flgW + c);
    const int fcrow = (l16 < DS) ? l16 : 4;
    int mtb[3];
    #pragma unroll
    for (int t = 0; t < 3; ++t) mtb[t] = ((c * 3 + t) * 16) * 512 + (l16 * 4 + quad) * 8;

    if (gmode == 0)
        run_loop<true >(out, h1_g, h2_g, Mlo_w, cg, flgW, flgPub,
                        Whh_s, WhhL_s, Mhi_s, fcW_s,
                        g, B0, j0, d0, tid, lane, l16, quad, bm0, fcrow, mtb,
                        zfrag, gi_st, bhh_l, c_l, fcb_l);
    else
        run_loop<false>(out, h1_g, h2_g, Mlo_w, cg, flgW, flgPub,
                        Whh_s, WhhL_s, Mhi_s, fcW_s,
                        g, B0, j0, d0, tid, lane, l16, quad, bm0, fcrow, mtb,
                        zfrag, gi_st, bhh_l, c_l, fcb_l);
}

extern "C" void kernel_launch(void* const* d_in, const int* in_sizes, int n_in,
                              void* d_out, int out_size, void* d_ws, size_t ws_size,
                              hipStream_t stream) {
    const float* z    = (const float*)d_in[0];
    // d_in[1] = e : unused by the reference computation
    const float* W_ih = (const float*)d_in[2];
    const float* W_hh = (const float*)d_in[3];
    const float* b_ih = (const float*)d_in[4];
    const float* b_hh = (const float*)d_in[5];
    const float* fc_W = (const float*)d_in[6];
    const float* fc_b = (const float*)d_in[7];
    float* out = (float*)d_out;

    // ws: [0,4K) flags(0..2047) + placement(2560,3072) | h1 2x | h2 2x | Mhi | Mlo
    char* w = (char*)d_ws;
    unsigned*       cnt = (unsigned*)w;
    unsigned short* h1  = (unsigned short*)(w + 4096);
    unsigned short* h2  = (unsigned short*)(w + 4096 + (size_t)4 * GHSZ);
    _Float16*       Mhi = (_Float16*)(w + 4096 + (size_t)8 * GHSZ);
    _Float16*       Mlo = (_Float16*)(w + 4096 + (size_t)8 * GHSZ + (size_t)3 * H_ * H_ * 2);

    // zero flags + h buffers (h_0 = 0); ws re-poisoned before every launch
    hipMemsetAsync(d_ws, 0, 4096 + (size_t)8 * GHSZ, stream);

    hipLaunchKernelGGL(msd_setup_M, dim3(768), dim3(256), 0, stream, W_ih, fc_W, Mhi, Mlo);
    hipLaunchKernelGGL(msd_gru_kernel, dim3(NG * CB), dim3(NT), 0, stream,
                       z, W_ih, W_hh, b_ih, b_hh, fc_W, fc_b, out, h1, h2, Mhi, Mlo, cnt);
}

// Round 5
// 4479.728 us; speedup vs baseline: 1.0239x; 1.0239x over previous
//
#include <hip/hip_runtime.h>
#include <hip/hip_fp16.h>

typedef _Float16 f16x8 __attribute__((ext_vector_type(8)));
typedef float f32x4 __attribute__((ext_vector_type(4)));
typedef unsigned long long u64;

#define NT 128      // 2 waves per block
#define B_ 256
#define D_ 128
#define T_ 512
#define H_ 512

#define NG 8        // batch groups (blockIdx&7 -> round-robin -> one XCD per group)
#define CB 32       // blocks per group
#define BS 32       // batch per group
#define HS 16       // h-cols per block
#define DS 4        // z-dims per block
#define GHSZ (NG * BS * H_)      // 131072 elems per h buffer

#define SC  2048.0f              // 2^11 prescale (keeps all f16 operands normal)
#define S1  (1.0f/2048.0f)       // 2^-11
#define S2  (1.0f/4194304.0f)    // 2^-22

#define MFMA16(A,B,C) __builtin_amdgcn_mfma_f32_16x16x32_f16((A),(B),(C),0,0,0)
#define ALD(p)   __hip_atomic_load((p),  __ATOMIC_RELAXED, __HIP_MEMORY_SCOPE_AGENT)

// ---------------- setup: M = W_ih @ fc_W, split hi/lo(x2^11), lo tiled ------
__global__ __launch_bounds__(256)
void msd_setup_M(const float* __restrict__ W_ih, const float* __restrict__ fc_W,
                 _Float16* __restrict__ Mhi,   // [3H][H] plain
                 _Float16* __restrict__ Mlo)   // fragment-tiled, x2^11
{
    const int r0 = (blockIdx.x >> 1) * 4;
    const int k  = ((blockIdx.x & 1) << 8) + threadIdx.x;
    for (int rr = 0; rr < 4; ++rr) {
        const int R = r0 + rr;
        const float* wrow = W_ih + (size_t)R * D_;
        float s = 0.0f;
        for (int d = 0; d < D_; ++d) s = fmaf(wrow[d], fc_W[(size_t)d * H_ + k], s);
        _Float16 hi = (_Float16)s;
        _Float16 lo = (_Float16)((s - (float)hi) * SC);
        Mhi[(size_t)R * H_ + k] = hi;
        const int t = R >> 9, jj = R & 511;
        const int c = jj >> 4, l16 = jj & 15;
        const int kt = k >> 5, quad = (k >> 3) & 3, j = k & 7;
        const size_t off = ((size_t)(((c * 3 + t) * 16 + kt) * 16 + l16) * 4 + quad) * 8 + j;
        Mlo[off] = lo;
    }
}

// ---------------- transport flavors -----------------------------------------
// L == true : XCD-LOCAL mode (runtime-verified via HW_REG_XCC_ID). Plain
//   write-through stores land in the local L2 after vmcnt(0); consumers use
//   volatile loads + buffer_inv (L1-only invalidate) for freshness. Sync =
//   per-(block,wave) dataflow flags (round-4-proven).
// L == false: AGENT mode (round-0 proven path): relaxed agent-scope atomics,
//   coherence point = MALL, central counter barrier. Fallback when a group
//   spans XCDs.
template<bool L> __device__ __forceinline__ u64 hld(const u64* p) {
    if constexpr (L) return *p;
    else return __hip_atomic_load(p, __ATOMIC_RELAXED, __HIP_MEMORY_SCOPE_AGENT);
}
template<bool L> __device__ __forceinline__ void hst(unsigned short* p, unsigned short v) {
    if constexpr (L) *p = v;
    else __hip_atomic_store(p, v, __ATOMIC_RELAXED, __HIP_MEMORY_SCOPE_AGENT);
}

// ---------------- main scan loop (templated on transport) -------------------
template<bool L>
__device__ __forceinline__
void run_loop(float* __restrict__ out,
              unsigned short* __restrict__ h1_g, unsigned short* __restrict__ h2_g,
              const _Float16* __restrict__ Mlo_w,
              unsigned* cg, const unsigned* flgW, volatile unsigned* flgPub,
              const _Float16* Whh_s, const _Float16* WhhL_s,
              const _Float16* Mhi_s, const _Float16* fcW_s,
              const int g, const int B0, const int j0, const int d0,
              const int tid, const int lane, const int l16, const int quad, const int bm0,
              const int fcrow, const int* mtb,
              f32x4& zfrag, f32x4* gi_st,
              const float* bhh_l, const float* c_l, const float fcb_l)
{
    float h_own[4] = {0.f, 0.f, 0.f, 0.f};

    for (int i = 1; i <= T_; ++i) {
        const unsigned tgt = (unsigned)(i - 1);
        if constexpr (L) {
            // dataflow wait: my wave-half's 32 producer flags >= i-1.
            // Stale-low volatile reads can't false-exit; inv-on-retry
            // guarantees progress (round-4-proven).
            const volatile unsigned* fp =
                (const volatile unsigned*)(flgW + (lane & 31));
            for (;;) {
                unsigned f = *fp;
                if (__ballot((int)(f >= tgt)) == ~0ull) break;
                asm volatile("buffer_inv" ::: "memory");
            }
            // Unconditional inv AFTER the wait: (a) drops 2-step-stale h lines
            // from L1, (b) its "memory" clobber pins the batched A-loads below
            // the flag wait (they're plain loads -> otherwise hoistable).
            asm volatile("buffer_inv" ::: "memory");
        }
        // AGENT mode: the barrier at the end of iteration i-1 provides
        // readiness; agent-scope loads bypass L1/L2 anyway.

        const size_t rb = (size_t)((i - 1) & 1) * GHSZ + (size_t)g * (BS * H_);
        const size_t wb = (size_t)(i & 1) * GHSZ + (size_t)g * (BS * H_);
        const u64* rh1 = (const u64*)(h1_g + rb);
        const u64* rh2 = (const u64*)(h2_g + rb);

        f32x4 acc_gh[3], acc2_gh[3], accM1[3], acc2_gi[3], acc_fc;
        {
            f32x4 z4 = {0.f, 0.f, 0.f, 0.f};
            #pragma unroll
            for (int t = 0; t < 3; ++t) { acc_gh[t] = z4; acc2_gh[t] = z4; accM1[t] = z4; acc2_gi[t] = z4; }
            acc_fc = z4;
        }

        // A-fragment base in u64 units: ((bm0+l16)*H_ + quad*8) f16 = /4 u64
        const size_t a64 = ((size_t)(bm0 + l16) * H_ + quad * 8) >> 2;

        // ---- phase A: issue ALL A-loads for the step (32 KB/wave = 128 VGPR).
        // One L2-latency exposure instead of ~8 partially-hidden ones.
        // Fully unrolled -> all Ar[] indices compile-time-static (no scratch).
        u64 Ar[16][4];
        #pragma unroll
        for (int kt = 0; kt < 16; ++kt) {
            Ar[kt][0] = hld<L>(rh1 + a64 + kt * 8);
            Ar[kt][1] = hld<L>(rh1 + a64 + kt * 8 + 1);
            Ar[kt][2] = hld<L>(rh2 + a64 + kt * 8);
            Ar[kt][3] = hld<L>(rh2 + a64 + kt * 8 + 1);
        }
        // ---- Mlo global-load software prefetch, depth 2 (hidden under 2 bodies)
        f16x8 Mlr[2][3];
        #pragma unroll
        for (int p = 0; p < 2; ++p)
            #pragma unroll
            for (int t = 0; t < 3; ++t)
                Mlr[p][t] = *(const f16x8*)(Mlo_w + mtb[t] + p * 512);

        // ---- phase B: 16 MFMA bodies, everything register/LDS-resident ------
        #pragma unroll
        for (int kt = 0; kt < 16; ++kt) {
            union { u64 q[2]; f16x8 v; } U1, U2;
            U1.q[0] = Ar[kt][0]; U1.q[1] = Ar[kt][1];
            U2.q[0] = Ar[kt][2]; U2.q[1] = Ar[kt][3];
            f16x8 Ah = U1.v;   // h x 2^11
            f16x8 Al = U2.v;   // resid x 2^22
            const int chunk = ((kt * 4 + quad) ^ (l16 & 7)) * 8;
            #pragma unroll
            for (int t = 0; t < 3; ++t) {
                const int row = (t * 16 + l16) * 512 + chunk;
                f16x8 Bwh = *(const f16x8*)(Whh_s + row);
                f16x8 Bwl = *(const f16x8*)(WhhL_s + row);
                acc_gh[t]  = MFMA16(Ah, Bwh, acc_gh[t]);    // scale 2^11
                acc2_gh[t] = MFMA16(Al, Bwh, acc2_gh[t]);   // scale 2^22
                acc2_gh[t] = MFMA16(Ah, Bwl, acc2_gh[t]);   // scale 2^22
                f16x8 Bmh = *(const f16x8*)(Mhi_s + row);
                accM1[t]   = MFMA16(Ah, Bmh, accM1[t]);
                acc2_gi[t] = MFMA16(Al, Bmh, acc2_gi[t]);
                acc2_gi[t] = MFMA16(Ah, Mlr[kt & 1][t], acc2_gi[t]);
            }
            if (kt < 14) {
                #pragma unroll
                for (int t = 0; t < 3; ++t)
                    Mlr[kt & 1][t] = *(const f16x8*)(Mlo_w + mtb[t] + (kt + 2) * 512);
            }
            f16x8 Bf = *(const f16x8*)(fcW_s + ((kt * 4 + quad) ^ (fcrow & 7)) * 8 + fcrow * 512);
            acc_fc = MFMA16(Ah, Bf, acc_fc);
        }

        if (i >= 2) {                // gi_st must be updated before h epilogue
            #pragma unroll
            for (int t = 0; t < 3; ++t)
                #pragma unroll
                for (int e = 0; e < 4; ++e)
                    gi_st[t][e] += accM1[t][e] * S1 + acc2_gi[t][e] * S2 + c_l[t];
        }
        if (i <= T_ - 1) {
            unsigned short* wh1 = h1_g + wb;
            unsigned short* wh2 = h2_g + wb;
            #pragma unroll
            for (int e = 0; e < 4; ++e) {
                float ghr = acc_gh[0][e] * S1 + acc2_gh[0][e] * S2 + bhh_l[0];
                float ghz = acc_gh[1][e] * S1 + acc2_gh[1][e] * S2 + bhh_l[1];
                float ghn = acc_gh[2][e] * S1 + acc2_gh[2][e] * S2 + bhh_l[2];
                float r  = 1.0f / (1.0f + __expf(-(gi_st[0][e] + ghr)));
                float zg = 1.0f / (1.0f + __expf(-(gi_st[1][e] + ghz)));
                float xn = gi_st[2][e] + r * ghn;
                float hn = (1.0f - zg) * tanhf(xn) + zg * h_own[e];
                h_own[e] = hn;
                const size_t o = (size_t)(bm0 + quad * 4 + e) * H_ + j0 + l16;
                float hs = hn * SC;
                _Float16 a1 = (_Float16)hs;
                _Float16 a2 = (_Float16)((hs - (float)a1) * SC);
                union { _Float16 f; unsigned short u; } c1, c2;
                c1.f = a1; c2.f = a2;
                hst<L>(wh1 + o, c1.u);   // LOCAL: write-through to local L2
                hst<L>(wh2 + o, c2.u);   // AGENT: relaxed agent-scope store
            }
            if constexpr (L) {
                // publish: drain the wave's h-stores into L2, then release the
                // per-(block,wave) flag with a plain write-through store.
                asm volatile("s_waitcnt vmcnt(0)" ::: "memory");
                if (lane == 0) *flgPub = (unsigned)i;
            } else {
                // __syncthreads() drains each wave's vmcnt(0) before s_barrier,
                // so all h-stores are at the MALL before tid0 arrives.
                __syncthreads();
                if (tid == 0) {
                    __hip_atomic_fetch_add(cg, 1u, __ATOMIC_RELAXED, __HIP_MEMORY_SCOPE_AGENT);
                    const unsigned target = (unsigned)(CB * i);
                    while (ALD(cg) < target) __builtin_amdgcn_s_sleep(1);
                }
                __syncthreads();
            }
        }
        if (i >= 2 && l16 < DS) {    // out-writes off the inter-block critical path
            const int tcol = i - 1;
            #pragma unroll
            for (int e = 0; e < 4; ++e) {
                zfrag[e] += acc_fc[e] * S1 + fcb_l;
                out[(size_t)(B0 + bm0 + quad * 4 + e) * (D_ * T_) + (size_t)(d0 + l16) * T_ + tcol] = zfrag[e];
            }
        }
    }
}

// ---------------- kernel ----------------------------------------------------
__global__ __launch_bounds__(NT, 1)
void msd_gru_kernel(const float* __restrict__ zin,
                    const float* __restrict__ W_ih,
                    const float* __restrict__ W_hh,
                    const float* __restrict__ b_ih,
                    const float* __restrict__ b_hh,
                    const float* __restrict__ fc_W,
                    const float* __restrict__ fc_b,
                    float* __restrict__ out,
                    unsigned short* __restrict__ h1_g,   // 2 x [NG][BS][H_] (h x 2^11, f16 bits)
                    unsigned short* __restrict__ h2_g,   // 2 x [NG][BS][H_] (resid x 2^22)
                    const _Float16* __restrict__ Mhi_w,  // [3H][H]
                    const _Float16* __restrict__ Mlo_w,  // tiled
                    unsigned* __restrict__ cnt)
{
    const int g   = blockIdx.x & 7;
    const int c   = blockIdx.x >> 3;
    const int B0  = g * BS;
    const int j0  = c * HS;
    const int d0  = c * DS;

    const int tid  = threadIdx.x;
    const int wave = tid >> 6;
    const int lane = tid & 63;
    const int l16  = lane & 15;
    const int quad = lane >> 4;
    const int bm0  = wave * 16;

    // LDS: (48*3 + 5) * 512 * 2 B = 152,576 B.  B-fragments XOR-swizzled:
    // chunk cc (8 f16) of row r stored at cc^(r&7)  -> conflict-free b128 reads.
    __shared__ __attribute__((aligned(16))) _Float16 Whh_s [48 * 512];
    __shared__ __attribute__((aligned(16))) _Float16 WhhL_s[48 * 512];  // x2^11
    __shared__ __attribute__((aligned(16))) _Float16 Mhi_s [48 * 512];
    __shared__ __attribute__((aligned(16))) _Float16 fcW_s [5 * 512];   // row 4 = zeros
    __shared__ int mode_s;

    // ===== phase -1: XCD placement detect (one-time) =========================
    // Group g runs L2-LOCAL iff all 32 of its blocks report the same XCC_ID.
    unsigned* xmask = cnt + 640;   // ws byte 2560, zeroed
    unsigned* ready = cnt + 768;   // ws byte 3072, zeroed
    if (tid == 0) {
        unsigned xcc;
        asm volatile("s_getreg_b32 %0, hwreg(HW_REG_XCC_ID)" : "=s"(xcc));
        __hip_atomic_fetch_or(xmask + g, 1u << (xcc & 31u), __ATOMIC_RELAXED, __HIP_MEMORY_SCOPE_AGENT);
        __hip_atomic_fetch_add(ready, 1u, __ATOMIC_RELAXED, __HIP_MEMORY_SCOPE_AGENT);
        while (ALD(ready) < (unsigned)(NG * CB)) __builtin_amdgcn_s_sleep(4);
        unsigned m = ALD(xmask + g);
        mode_s = (m & (m - 1u)) ? 1 : 0;   // >1 XCD bit set -> AGENT fallback
    }

    // ===== phase 0: z0 into scratch (reuse Mhi_s region), bootstrap state ====
    float* z0s = (float*)Mhi_s;   // 16 KB < 48 KB
    for (int idx = tid; idx < BS * D_; idx += NT) {
        int b = idx >> 7, d = idx & (D_ - 1);
        z0s[idx] = zin[(size_t)(B0 + b) * (D_ * T_) + (size_t)d * T_];
    }
    __syncthreads();

    f32x4 zfrag;
    #pragma unroll
    for (int e = 0; e < 4; ++e)
        zfrag[e] = (l16 < DS) ? z0s[(bm0 + quad * 4 + e) * D_ + d0 + l16] : 0.0f;
    if (l16 < DS) {
        #pragma unroll
        for (int e = 0; e < 4; ++e)
            out[(size_t)(B0 + bm0 + quad * 4 + e) * (D_ * T_) + (size_t)(d0 + l16) * T_] = zfrag[e];
    }
    // gi_1 = W_ih @ z0 + b_ih (exact fp32); c = W_ih @ fc_b; b_hh per lane
    f32x4 gi_st[3];
    float bhh_l[3], c_l[3];
    for (int t = 0; t < 3; ++t) {
        const int gr = t * H_ + j0 + l16;
        const float* wrow = W_ih + (size_t)gr * D_;
        bhh_l[t] = b_hh[gr];
        float s[4] = {b_ih[gr], b_ih[gr], b_ih[gr], b_ih[gr]};
        float cc = 0.0f;
        for (int d = 0; d < D_; ++d) {
            float wv = wrow[d];
            cc = fmaf(wv, fc_b[d], cc);
            #pragma unroll
            for (int e = 0; e < 4; ++e)
                s[e] = fmaf(wv, z0s[(bm0 + quad * 4 + e) * D_ + d], s[e]);
        }
        c_l[t] = cc;
        #pragma unroll
        for (int e = 0; e < 4; ++e) gi_st[t][e] = s[e];
    }
    const float fcb_l = (l16 < DS) ? fc_b[d0 + l16] : 0.0f;
    __syncthreads();   // z0s dead -> Mhi_s region reusable

    // ===== phase 1: stage weights (hi fp16 + lo fp16 x2^11), swizzled ========
    for (int idx = tid; idx < 48 * H_; idx += NT) {
        int r = idx >> 9, k = idx & (H_ - 1);
        int gr = (r >> 4) * H_ + j0 + (r & 15);
        int ccn = k >> 3, j = k & 7;
        int pos = r * 512 + (((ccn ^ (r & 7)) << 3) | j);
        float w = W_hh[(size_t)gr * H_ + k];
        _Float16 hi = (_Float16)w;
        Whh_s [pos] = hi;
        WhhL_s[pos] = (_Float16)((w - (float)hi) * SC);
        Mhi_s [pos] = Mhi_w[(size_t)gr * H_ + k];
    }
    for (int idx = tid; idx < 5 * H_; idx += NT) {
        int r = idx >> 9, k = idx & (H_ - 1);
        int ccn = k >> 3, j = k & 7;
        int pos = r * 512 + (((ccn ^ (r & 7)) << 3) | j);
        float v = (r < DS) ? fc_W[(size_t)(d0 + r) * H_ + k] : 0.0f;
        fcW_s[pos] = (_Float16)v;
    }
    __syncthreads();    // also publishes mode_s

    const int gmode = mode_s;
    unsigned* cg = cnt + g * 64;                           // AGENT central counter
    const unsigned* flgW = cnt + (((g << 1) | wave) << 5); // LOCAL: wave-half's 32 flags
    volatile unsigned* flgPub = (volatile unsigned*)(flgW + c);
    const int fcrow = (l16 < DS) ? l16 : 4;
    int mtb[3];
    #pragma unroll
    for (int t = 0; t < 3; ++t) mtb[t] = ((c * 3 + t) * 16) * 512 + (l16 * 4 + quad) * 8;

    if (gmode == 0)
        run_loop<true >(out, h1_g, h2_g, Mlo_w, cg, flgW, flgPub,
                        Whh_s, WhhL_s, Mhi_s, fcW_s,
                        g, B0, j0, d0, tid, lane, l16, quad, bm0, fcrow, mtb,
                        zfrag, gi_st, bhh_l, c_l, fcb_l);
    else
        run_loop<false>(out, h1_g, h2_g, Mlo_w, cg, flgW, flgPub,
                        Whh_s, WhhL_s, Mhi_s, fcW_s,
                        g, B0, j0, d0, tid, lane, l16, quad, bm0, fcrow, mtb,
                        zfrag, gi_st, bhh_l, c_l, fcb_l);
}

extern "C" void kernel_launch(void* const* d_in, const int* in_sizes, int n_in,
                              void* d_out, int out_size, void* d_ws, size_t ws_size,
                              hipStream_t stream) {
    const float* z    = (const float*)d_in[0];
    // d_in[1] = e : unused by the reference computation
    const float* W_ih = (const float*)d_in[2];
    const float* W_hh = (const float*)d_in[3];
    const float* b_ih = (const float*)d_in[4];
    const float* b_hh = (const float*)d_in[5];
    const float* fc_W = (const float*)d_in[6];
    const float* fc_b = (const float*)d_in[7];
    float* out = (float*)d_out;

    // ws: [0,4K) flags(0..2047) + placement(2560,3072) | h1 2x | h2 2x | Mhi | Mlo
    char* w = (char*)d_ws;
    unsigned*       cnt = (unsigned*)w;
    unsigned short* h1  = (unsigned short*)(w + 4096);
    unsigned short* h2  = (unsigned short*)(w + 4096 + (size_t)4 * GHSZ);
    _Float16*       Mhi = (_Float16*)(w + 4096 + (size_t)8 * GHSZ);
    _Float16*       Mlo = (_Float16*)(w + 4096 + (size_t)8 * GHSZ + (size_t)3 * H_ * H_ * 2);

    // zero flags + h buffers (h_0 = 0); ws re-poisoned before every launch
    hipMemsetAsync(d_ws, 0, 4096 + (size_t)8 * GHSZ, stream);

    hipLaunchKernelGGL(msd_setup_M, dim3(768), dim3(256), 0, stream, W_ih, fc_W, Mhi, Mlo);
    hipLaunchKernelGGL(msd_gru_kernel, dim3(NG * CB), dim3(NT), 0, stream,
                       z, W_ih, W_hh, b_ih, b_hh, fc_W, fc_b, out, h1, h2, Mhi, Mlo, cnt);
}

// Round 6
// 2367.507 us; speedup vs baseline: 1.9374x; 1.8922x over previous
//
#include <hip/hip_runtime.h>
#include <hip/hip_fp16.h>

typedef _Float16 f16x8 __attribute__((ext_vector_type(8)));
typedef float f32x4 __attribute__((ext_vector_type(4)));
typedef unsigned long long u64;

#define NT 512      // 8 waves: (bh, kq) = (batch-half, K-quarter)
#define B_ 256
#define D_ 128
#define T_ 512
#define H_ 512

#define NG 8        // batch groups (blockIdx&7 -> round-robin -> one XCD per group)
#define CB 32       // blocks per group
#define BS 32       // batch per group
#define HS 16       // h-cols per block
#define DS 4        // z-dims per block
#define GHSZ (NG * BS * H_)      // 131072 elems per h buffer

#define SC  2048.0f              // 2^11 prescale (keeps all f16 operands normal)
#define S1  (1.0f/2048.0f)       // 2^-11
#define S2  (1.0f/4194304.0f)    // 2^-22

#define MFMA16(A,B,C) __builtin_amdgcn_mfma_f32_16x16x32_f16((A),(B),(C),0,0,0)
#define ALD(p)   __hip_atomic_load((p),  __ATOMIC_RELAXED, __HIP_MEMORY_SCOPE_AGENT)

// ---------------- setup: M = W_ih @ fc_W, split hi/lo(x2^11), BOTH tiled ----
__global__ __launch_bounds__(256)
void msd_setup_M(const float* __restrict__ W_ih, const float* __restrict__ fc_W,
                 _Float16* __restrict__ Mhi,   // fragment-tiled
                 _Float16* __restrict__ Mlo)   // fragment-tiled, x2^11
{
    const int r0 = (blockIdx.x >> 1) * 4;
    const int k  = ((blockIdx.x & 1) << 8) + threadIdx.x;
    for (int rr = 0; rr < 4; ++rr) {
        const int R = r0 + rr;
        const float* wrow = W_ih + (size_t)R * D_;
        float s = 0.0f;
        for (int d = 0; d < D_; ++d) s = fmaf(wrow[d], fc_W[(size_t)d * H_ + k], s);
        _Float16 hi = (_Float16)s;
        _Float16 lo = (_Float16)((s - (float)hi) * SC);
        const int t = R >> 9, jj = R & 511;
        const int c = jj >> 4, l16 = jj & 15;
        const int kt = k >> 5, quad = (k >> 3) & 3, j = k & 7;
        const size_t off = ((size_t)(((c * 3 + t) * 16 + kt) * 16 + l16) * 4 + quad) * 8 + j;
        Mhi[off] = hi;
        Mlo[off] = lo;
    }
}

// ---------------- transport flavors (round-2/4/5 proven) --------------------
template<bool L> __device__ __forceinline__ u64 hld(const u64* p) {
    if constexpr (L) return *p;
    else return __hip_atomic_load(p, __ATOMIC_RELAXED, __HIP_MEMORY_SCOPE_AGENT);
}
template<bool L> __device__ __forceinline__ void hst(unsigned short* p, unsigned short v) {
    if constexpr (L) *p = v;
    else __hip_atomic_store(p, v, __ATOMIC_RELAXED, __HIP_MEMORY_SCOPE_AGENT);
}

// ---------------- main scan loop (templated on transport) -------------------
// 8-wave K-split: wave (bh,kq) computes kt in [4kq,4kq+4) for batch-half bh
// (40 MFMA / 28 LDS-reads per wave per step), partials exchanged via LDS
// scratch; each wave owns ONE e (batch row bm0+quad*4+kq) for the epilogue.
// M (static) lives in 96 VGPRs, hoisted out of the T-loop entirely.
template<bool L>
__device__ __forceinline__
void run_loop(float* __restrict__ out,
              unsigned short* __restrict__ h1_g, unsigned short* __restrict__ h2_g,
              const _Float16* __restrict__ Mhi_w, const _Float16* __restrict__ Mlo_w,
              unsigned* cg, const unsigned* flgW, volatile unsigned* flgPub,
              const _Float16* Whh_s, const _Float16* WhhL_s, const _Float16* fcW_s,
              float* scr0,
              const int g, const int B0, const int j0, const int d0,
              const int tid, const int lane, const int l16, const int quad,
              const int bh, const int kq, const int bm0,
              const int fcrow, const int* mtb,
              float zfrag, const float* gi0,
              const float* bhh_l, const float* c_l, const float fcb_l)
{
    float gi_st[3] = {gi0[0], gi0[1], gi0[2]};
    float h_own = 0.0f;
    const int ktb = kq * 4;
    const int r_own = bm0 + quad * 4 + kq;
    // A-fragment base in u64 units: ((bm0+l16)*H_ + quad*8) f16 = /4 u64
    const size_t a64 = ((size_t)(bm0 + l16) * H_ + quad * 8) >> 2;

    // ---- hoist the static M tiles into registers: 24 x f16x8 = 96 VGPR.
    // These never change across steps -> zero per-step M traffic.
    f16x8 Mh[4][3], Ml[4][3];
    #pragma unroll
    for (int ktl = 0; ktl < 4; ++ktl)
        #pragma unroll
        for (int t = 0; t < 3; ++t) {
            Mh[ktl][t] = *(const f16x8*)(Mhi_w + mtb[t] + (ktb + ktl) * 512);
            Ml[ktl][t] = *(const f16x8*)(Mlo_w + mtb[t] + (ktb + ktl) * 512);
        }

    for (int i = 1; i <= T_; ++i) {
        const unsigned tgt = (unsigned)(i - 1);
        if constexpr (L) {
            // dataflow wait: all 32 block-flags of this group >= i-1.
            // Stale-low volatile reads can't false-exit; inv-on-retry
            // guarantees progress (round-4/5 proven poll).
            const volatile unsigned* fp =
                (const volatile unsigned*)(flgW + (lane & 31));
            for (;;) {
                unsigned f = *fp;
                if (__ballot((int)(f >= tgt)) == ~0ull) break;
                asm volatile("buffer_inv" ::: "memory");
            }
            // drop 2-step-stale h lines from L1; memory clobber pins the
            // A-loads below the wait.
            asm volatile("buffer_inv" ::: "memory");
        }
        // AGENT mode: the barrier at the end of iteration i-1 provides readiness.

        const size_t rb = (size_t)((i - 1) & 1) * GHSZ + (size_t)g * (BS * H_);
        const size_t wb = (size_t)(i & 1) * GHSZ + (size_t)g * (BS * H_);
        const u64* rh1 = (const u64*)(h1_g + rb);
        const u64* rh2 = (const u64*)(h2_g + rb);

        // ---- batch this wave's A-loads (4 chunks, 32 VGPR), one exposure.
        u64 Ar[4][4];
        #pragma unroll
        for (int ktl = 0; ktl < 4; ++ktl) {
            const int ktg = ktb + ktl;
            Ar[ktl][0] = hld<L>(rh1 + a64 + ktg * 8);
            Ar[ktl][1] = hld<L>(rh1 + a64 + ktg * 8 + 1);
            Ar[ktl][2] = hld<L>(rh2 + a64 + ktg * 8);
            Ar[ktl][3] = hld<L>(rh2 + a64 + ktg * 8 + 1);
        }

        f32x4 acc_gh[3], acc2_gh[3], accM1[3], acc2_gi[3], acc_fc;
        {
            f32x4 z4 = {0.f, 0.f, 0.f, 0.f};
            #pragma unroll
            for (int t = 0; t < 3; ++t) { acc_gh[t] = z4; acc2_gh[t] = z4; accM1[t] = z4; acc2_gi[t] = z4; }
            acc_fc = z4;
        }

        // ---- 4 MFMA bodies (this wave's K-quarter) -------------------------
        #pragma unroll
        for (int ktl = 0; ktl < 4; ++ktl) {
            const int ktg = ktb + ktl;
            union { u64 q[2]; f16x8 v; } U1, U2;
            U1.q[0] = Ar[ktl][0]; U1.q[1] = Ar[ktl][1];
            U2.q[0] = Ar[ktl][2]; U2.q[1] = Ar[ktl][3];
            f16x8 Ah = U1.v;   // h x 2^11
            f16x8 Al = U2.v;   // resid x 2^22
            const int chunk = ((ktg * 4 + quad) ^ (l16 & 7)) * 8;
            #pragma unroll
            for (int t = 0; t < 3; ++t) {
                const int row = (t * 16 + l16) * 512 + chunk;
                f16x8 Bwh = *(const f16x8*)(Whh_s + row);
                f16x8 Bwl = *(const f16x8*)(WhhL_s + row);
                acc_gh[t]  = MFMA16(Ah, Bwh, acc_gh[t]);    // scale 2^11
                acc2_gh[t] = MFMA16(Al, Bwh, acc2_gh[t]);   // scale 2^22
                acc2_gh[t] = MFMA16(Ah, Bwl, acc2_gh[t]);   // scale 2^22
                accM1[t]   = MFMA16(Ah, Mh[ktl][t], accM1[t]);
                acc2_gi[t] = MFMA16(Al, Mh[ktl][t], acc2_gi[t]);
                acc2_gi[t] = MFMA16(Ah, Ml[ktl][t], acc2_gi[t]);
            }
            // lanes l16>=DS read fcW row 0; their output columns are discarded.
            f16x8 Bf = *(const f16x8*)(fcW_s + ((ktg * 4 + quad) ^ fcrow) * 8 + fcrow * 512);
            acc_fc = MFMA16(Ah, Bf, acc_fc);
        }

        // ---- pre-combine partials and exchange across the 4 kq waves -------
        float Pgh[3][4], Pgi[3][4], Pfc[4];
        #pragma unroll
        for (int t = 0; t < 3; ++t)
            #pragma unroll
            for (int e = 0; e < 4; ++e) {
                Pgh[t][e] = acc_gh[t][e] * S1 + acc2_gh[t][e] * S2;
                Pgi[t][e] = accM1[t][e] * S1 + acc2_gi[t][e] * S2;
            }
        #pragma unroll
        for (int e = 0; e < 4; ++e) Pfc[e] = acc_fc[e] * S1;

        #pragma unroll
        for (int e = 0; e < 4; ++e) {
            if (e == kq) continue;
            const int si = (kq < e) ? kq : kq - 1;
            float* sp = scr0 + ((((bh * 4 + e) * 3 + si) * 64 + lane) * 9);
            sp[0] = Pgh[0][e]; sp[1] = Pgh[1][e]; sp[2] = Pgh[2][e];
            sp[3] = Pgi[0][e]; sp[4] = Pgi[1][e]; sp[5] = Pgi[2][e];
            sp[6] = Pfc[e];
        }
        __syncthreads();   // barrier1: exchange visible
        float tgh0 = Pgh[0][kq], tgh1 = Pgh[1][kq], tgh2 = Pgh[2][kq];
        float tgi0 = Pgi[0][kq], tgi1 = Pgi[1][kq], tgi2 = Pgi[2][kq];
        float tfc  = Pfc[kq];
        #pragma unroll
        for (int s = 0; s < 3; ++s) {
            const float* sp = scr0 + ((((bh * 4 + kq) * 3 + s) * 64 + lane) * 9);
            tgh0 += sp[0]; tgh1 += sp[1]; tgh2 += sp[2];
            tgi0 += sp[3]; tgi1 += sp[4]; tgi2 += sp[5];
            tfc  += sp[6];
        }

        if (i >= 2) {
            gi_st[0] += tgi0 + c_l[0];
            gi_st[1] += tgi1 + c_l[1];
            gi_st[2] += tgi2 + c_l[2];
            if (l16 < DS) zfrag += tfc + fcb_l;
        }
        if (i <= T_ - 1) {
            float ghr = tgh0 + bhh_l[0];
            float ghz = tgh1 + bhh_l[1];
            float ghn = tgh2 + bhh_l[2];
            float r  = 1.0f / (1.0f + __expf(-(gi_st[0] + ghr)));
            float zg = 1.0f / (1.0f + __expf(-(gi_st[1] + ghz)));
            float xn = gi_st[2] + r * ghn;
            float hn = (1.0f - zg) * tanhf(xn) + zg * h_own;
            h_own = hn;
            const size_t o = (size_t)r_own * H_ + j0 + l16;
            float hs = hn * SC;
            _Float16 a1 = (_Float16)hs;
            _Float16 a2 = (_Float16)((hs - (float)a1) * SC);
            union { _Float16 f; unsigned short u; } c1, c2;
            c1.f = a1; c2.f = a2;
            hst<L>(h1_g + wb + o, c1.u);   // LOCAL: write-through to local L2
            hst<L>(h2_g + wb + o, c2.u);
        }
        // barrier2: __syncthreads drains each wave's vmcnt(0) -> all 8 waves'
        // h-stores are at the coherence point; also guards scr reuse.
        __syncthreads();
        if constexpr (L) {
            if (tid == 0) *flgPub = (unsigned)i;   // one flag per block
        } else {
            if (tid == 0) {
                __hip_atomic_fetch_add(cg, 1u, __ATOMIC_RELAXED, __HIP_MEMORY_SCOPE_AGENT);
                const unsigned target = (unsigned)(CB * i);
                while (ALD(cg) < target) __builtin_amdgcn_s_sleep(1);
            }
            __syncthreads();
        }
        // out-writes off the inter-block critical path
        if (i >= 2 && l16 < DS)
            out[(size_t)(B0 + r_own) * (D_ * T_) + (size_t)(d0 + l16) * T_ + (i - 1)] = zfrag;
    }
}

// ---------------- kernel ----------------------------------------------------
__global__ __launch_bounds__(NT, 2)   // 8 waves, 1 block/CU, VGPR cap 256
void msd_gru_kernel(const float* __restrict__ zin,
                    const float* __restrict__ W_ih,
                    const float* __restrict__ W_hh,
                    const float* __restrict__ b_ih,
                    const float* __restrict__ b_hh,
                    const float* __restrict__ fc_W,
                    const float* __restrict__ fc_b,
                    float* __restrict__ out,
                    unsigned short* __restrict__ h1_g,   // 2 x [NG][BS][H_] (h x 2^11)
                    unsigned short* __restrict__ h2_g,   // 2 x [NG][BS][H_] (resid x 2^22)
                    const _Float16* __restrict__ Mhi_w,  // tiled
                    const _Float16* __restrict__ Mlo_w,  // tiled
                    unsigned* __restrict__ cnt)
{
    const int g   = blockIdx.x & 7;
    const int c   = blockIdx.x >> 3;
    const int B0  = g * BS;
    const int j0  = c * HS;
    const int d0  = c * DS;

    const int tid  = threadIdx.x;
    const int wave = tid >> 6;
    const int lane = tid & 63;
    const int l16  = lane & 15;
    const int quad = lane >> 4;
    const int bh   = wave >> 2;     // batch-half
    const int kq   = wave & 3;      // K-quarter (also the owned e)
    const int bm0  = bh * 16;
    const int r_own = bm0 + quad * 4 + kq;

    // LDS: Whh 48K + WhhL 48K + fcW 4K + scratch 54K = ~154 KB.
    // Weight rows XOR-swizzled: chunk cc of row r at cc^(r&7) -> conflict-free
    // b128 reads. Scratch inner pad 9 (coprime 32) -> conflict-free exchange.
    __shared__ __attribute__((aligned(16))) _Float16 Whh_s [48 * 512];
    __shared__ __attribute__((aligned(16))) _Float16 WhhL_s[48 * 512];  // x2^11
    __shared__ __attribute__((aligned(16))) _Float16 fcW_s [4 * 512];
    __shared__ __attribute__((aligned(16))) float    scr   [2 * 4 * 3 * 64 * 9];
    __shared__ int mode_s;

    // ===== phase -1: XCD placement detect (one-time) =========================
    unsigned* xmask = cnt + 640;   // ws byte 2560, zeroed
    unsigned* ready = cnt + 768;   // ws byte 3072, zeroed
    if (tid == 0) {
        unsigned xcc;
        asm volatile("s_getreg_b32 %0, hwreg(HW_REG_XCC_ID)" : "=s"(xcc));
        __hip_atomic_fetch_or(xmask + g, 1u << (xcc & 31u), __ATOMIC_RELAXED, __HIP_MEMORY_SCOPE_AGENT);
        __hip_atomic_fetch_add(ready, 1u, __ATOMIC_RELAXED, __HIP_MEMORY_SCOPE_AGENT);
        while (ALD(ready) < (unsigned)(NG * CB)) __builtin_amdgcn_s_sleep(4);
        unsigned m = ALD(xmask + g);
        mode_s = (m & (m - 1u)) ? 1 : 0;   // >1 XCD bit set -> AGENT fallback
    }

    // ===== phase 0: z0 into scratch (reuse Whh_s region), bootstrap state ====
    float* z0s = (float*)Whh_s;   // 16 KB < 48 KB
    for (int idx = tid; idx < BS * D_; idx += NT) {
        int b = idx >> 7, d = idx & (D_ - 1);
        z0s[idx] = zin[(size_t)(B0 + b) * (D_ * T_) + (size_t)d * T_];
    }
    __syncthreads();

    float zfrag = (l16 < DS) ? z0s[r_own * D_ + d0 + l16] : 0.0f;
    if (l16 < DS)
        out[(size_t)(B0 + r_own) * (D_ * T_) + (size_t)(d0 + l16) * T_] = zfrag;
    // gi_1 = W_ih @ z0 + b_ih (exact fp32, own e only); c = W_ih @ fc_b
    float gi0[3], bhh_l[3], c_l[3];
    for (int t = 0; t < 3; ++t) {
        const int gr = t * H_ + j0 + l16;
        const float* wrow = W_ih + (size_t)gr * D_;
        bhh_l[t] = b_hh[gr];
        float s = b_ih[gr], cc = 0.0f;
        for (int d = 0; d < D_; ++d) {
            float wv = wrow[d];
            cc = fmaf(wv, fc_b[d], cc);
            s  = fmaf(wv, z0s[r_own * D_ + d], s);
        }
        c_l[t] = cc;
        gi0[t] = s;
    }
    const float fcb_l = (l16 < DS) ? fc_b[d0 + l16] : 0.0f;
    __syncthreads();   // z0s dead -> Whh_s region reusable

    // ===== phase 1: stage Whh hi/lo + fcW, swizzled ==========================
    for (int idx = tid; idx < 48 * H_; idx += NT) {
        int r = idx >> 9, k = idx & (H_ - 1);
        int gr = (r >> 4) * H_ + j0 + (r & 15);
        int pos = r * 512 + ((((k >> 3) ^ (r & 7)) << 3) | (k & 7));
        float w = W_hh[(size_t)gr * H_ + k];
        _Float16 hi = (_Float16)w;
        Whh_s [pos] = hi;
        WhhL_s[pos] = (_Float16)((w - (float)hi) * SC);
    }
    for (int idx = tid; idx < 4 * H_; idx += NT) {
        int r = idx >> 9, k = idx & (H_ - 1);
        int pos = r * 512 + ((((k >> 3) ^ r) << 3) | (k & 7));
        fcW_s[pos] = (_Float16)fc_W[(size_t)(d0 + r) * H_ + k];
    }
    __syncthreads();    // also publishes mode_s

    const int gmode = mode_s;
    const unsigned* flgW = cnt + g * 32;                    // this group's 32 block flags
    volatile unsigned* flgPub = (volatile unsigned*)(cnt + g * 32 + c);
    unsigned* cg = cnt + 256 + g * 32;                      // AGENT central counters
    const int fcrow = (l16 < DS) ? l16 : 0;
    int mtb[3];
    #pragma unroll
    for (int t = 0; t < 3; ++t) mtb[t] = ((c * 3 + t) * 16) * 512 + (l16 * 4 + quad) * 8;

    if (gmode == 0)
        run_loop<true >(out, h1_g, h2_g, Mhi_w, Mlo_w, cg, flgW, flgPub,
                        Whh_s, WhhL_s, fcW_s, scr,
                        g, B0, j0, d0, tid, lane, l16, quad, bh, kq, bm0,
                        fcrow, mtb, zfrag, gi0, bhh_l, c_l, fcb_l);
    else
        run_loop<false>(out, h1_g, h2_g, Mhi_w, Mlo_w, cg, flgW, flgPub,
                        Whh_s, WhhL_s, fcW_s, scr,
                        g, B0, j0, d0, tid, lane, l16, quad, bh, kq, bm0,
                        fcrow, mtb, zfrag, gi0, bhh_l, c_l, fcb_l);
}

extern "C" void kernel_launch(void* const* d_in, const int* in_sizes, int n_in,
                              void* d_out, int out_size, void* d_ws, size_t ws_size,
                              hipStream_t stream) {
    const float* z    = (const float*)d_in[0];
    // d_in[1] = e : unused by the reference computation
    const float* W_ih = (const float*)d_in[2];
    const float* W_hh = (const float*)d_in[3];
    const float* b_ih = (const float*)d_in[4];
    const float* b_hh = (const float*)d_in[5];
    const float* fc_W = (const float*)d_in[6];
    const float* fc_b = (const float*)d_in[7];
    float* out = (float*)d_out;

    // ws: [0,4K) flags(0..1023) + agent-counters(1024..2047) + placement(2560,3072)
    //     | h1 2x | h2 2x | Mhi(tiled) | Mlo(tiled)
    char* w = (char*)d_ws;
    unsigned*       cnt = (unsigned*)w;
    unsigned short* h1  = (unsigned short*)(w + 4096);
    unsigned short* h2  = (unsigned short*)(w + 4096 + (size_t)4 * GHSZ);
    _Float16*       Mhi = (_Float16*)(w + 4096 + (size_t)8 * GHSZ);
    _Float16*       Mlo = (_Float16*)(w + 4096 + (size_t)8 * GHSZ + (size_t)3 * H_ * H_ * 2);

    // zero flags + h buffers (h_0 = 0); ws re-poisoned before every launch
    hipMemsetAsync(d_ws, 0, 4096 + (size_t)8 * GHSZ, stream);

    hipLaunchKernelGGL(msd_setup_M, dim3(768), dim3(256), 0, stream, W_ih, fc_W, Mhi, Mlo);
    hipLaunchKernelGGL(msd_gru_kernel, dim3(NG * CB), dim3(NT), 0, stream,
                       z, W_ih, W_hh, b_ih, b_hh, fc_W, fc_b, out, h1, h2, Mhi, Mlo, cnt);
}